// Round 6
// baseline (2038.487 us; speedup 1.0000x reference)
//
#include <hip/hip_runtime.h>
#include <stdint.h>

#define Cc   16
#define HIDD 128
#define Bn   8
#define Hh   256
#define Ww   256
#define HW   (Hh * Ww)         // 65536
#define NPIX (Bn * HW)         // 524288
#define NSTEPS 32

typedef _Float16 half8 __attribute__((ext_vector_type(8)));
typedef float floatx16 __attribute__((ext_vector_type(16)));

// ---------------- JAX threefry2x32 (20 rounds), host+device ----------------
__host__ __device__ inline void threefry2x32(uint32_t k1, uint32_t k2,
                                             uint32_t x0, uint32_t x1,
                                             uint32_t& o0, uint32_t& o1) {
  const uint32_t ks2 = k1 ^ k2 ^ 0x1BD11BDAu;
  uint32_t v0 = x0 + k1;
  uint32_t v1 = x1 + k2;
#define ROTL32(x, n) (((x) << (n)) | ((x) >> (32 - (n))))
#define R4(a, b, c, d)                                    \
  { v0 += v1; v1 = ROTL32(v1, a); v1 ^= v0;               \
    v0 += v1; v1 = ROTL32(v1, b); v1 ^= v0;               \
    v0 += v1; v1 = ROTL32(v1, c); v1 ^= v0;               \
    v0 += v1; v1 = ROTL32(v1, d); v1 ^= v0; }
  R4(13, 15, 26, 6)   v0 += k2;  v1 += ks2 + 1u;
  R4(17, 29, 16, 24)  v0 += ks2; v1 += k1 + 2u;
  R4(13, 15, 26, 6)   v0 += k1;  v1 += k2 + 3u;
  R4(17, 29, 16, 24)  v0 += k2;  v1 += ks2 + 4u;
  R4(13, 15, 26, 6)   v0 += ks2; v1 += k1 + 5u;
#undef R4
#undef ROTL32
  o0 = v0;
  o1 = v1;
}

__device__ inline uint32_t pk2(_Float16 a, _Float16 b) {
  union { _Float16 h[2]; uint32_t u; } t;
  t.h[0] = a; t.h[1] = b;
  return t.u;
}
__device__ inline half8 mk8(uint32_t a, uint32_t b, uint32_t c, uint32_t d) {
  union { uint32_t u[4]; half8 h; } t;
  t.u[0] = a; t.u[1] = b; t.u[2] = c; t.u[3] = d;
  return t.h;
}

// v_permlane32_swap_b32: a.lanes[32:63] <-> b.lanes[0:31] (both regs updated).
__device__ inline void pl32swap(uint32_t& a, uint32_t& b) {
  asm("v_permlane32_swap_b32 %0, %1" : "+v"(a), "+v"(b));
}

// ---- prep: pack W0^T / W1p^T into 32x32x16 A-fragment order (f16 hi/lo) ----
// Hidden units are PERMUTED so GEMM1's D-register layout row=(r&3)+8*(r>>2)+4*h8
// lines up with GEMM2's B k-slot layout k=8*h8+j (bit-exact relabeling).
// W1's M rows permuted so each half-wave holds exactly the 8 channels it stores.
__global__ __launch_bounds__(256) void k_prep(const float* __restrict__ wfc0,
                                              const float* __restrict__ wfc1,
                                              unsigned short* __restrict__ wf) {
  const int idx = blockIdx.x * 256 + threadIdx.x;
  if (idx < 12288) {
    const int j = idx & 7;
    const int t = idx >> 3;
    const int lane = t & 63;
    const int t2 = t >> 6;
    const int spl = t2 & 1;
    const int fk = t2 >> 1;
    const int kt = fk % 3;
    const int Mt = fk / 3;
    const int rho = lane & 31;
    const int r16 = rho & 15;
    const int mlog = Mt * 32 + (rho >> 4) * 16
                   + ((r16 >> 2) & 1) * 8 + ((r16 >> 3) & 1) * 4 + (r16 & 3);
    const int k = kt * 16 + (lane >> 5) * 8 + j;
    const float v = wfc0[k * HIDD + mlog];
    const _Float16 hi = (_Float16)v;
    const _Float16 r = spl ? (_Float16)(v - (float)hi) : hi;
    union { _Float16 h; unsigned short s; } cv; cv.h = r;
    wf[idx] = cv.s;
  } else if (idx < 20480) {
    const int idx2 = idx - 12288;
    const int j = idx2 & 7;
    const int t = idx2 >> 3;
    const int lane = t & 63;
    const int t2 = t >> 6;
    const int spl = t2 & 1;
    const int kt2 = t2 >> 1;
    const int rho = lane & 31;
    int ml = -1;                       // dx channel = ml+3
    if (rho < 4) ml = rho;             // phys 0..3  -> ch 3..6   (h8=0 r0..3)
    else if (rho < 8) ml = rho + 1;    // phys 4..7  -> ch 8..11  (h8=1 r0..3)
    else if (rho == 8) ml = 4;         // phys 8     -> ch 7      (h8=0 r4)
    else if (rho >= 12 && rho < 16) ml = rho - 3;  // phys 12..15 -> ch 12..15
    const int k = kt2 * 16 + (lane >> 5) * 8 + j;  // logical hid (unchanged)
    const float v = (ml >= 0) ? wfc1[k * 16 + (ml + 3)] : 0.f;
    const _Float16 hi = (_Float16)v;
    const _Float16 r = spl ? (_Float16)(v - (float)hi) : hi;
    union { _Float16 h; unsigned short s; } cv; cv.h = r;
    wf[idx] = cv.s;
  }
}

// ---------------- NCHW -> NHWC state init ----------------
__global__ __launch_bounds__(256) void k_nchw_to_nhwc(const float* __restrict__ x,
                                                      float* __restrict__ st) {
  const int p = blockIdx.x * 256 + threadIdx.x;
  const int b = p >> 16;
  const int hw = p & 65535;
  const float* src = x + (size_t)b * (Cc * HW) + hw;
  float v[16];
#pragma unroll
  for (int c = 0; c < 16; c++) v[c] = src[(size_t)c * HW];
  float4* dst = (float4*)(st + (size_t)p * 16);
#pragma unroll
  for (int q = 0; q < 4; q++)
    dst[q] = make_float4(v[4 * q], v[4 * q + 1], v[4 * q + 2], v[4 * q + 3]);
}

// ---------------- One NCA step: perception (VALU) + MLP (MFMA) ----------------
__global__ __launch_bounds__(256, 4) void k_step(const float* __restrict__ in,
                                                 float* __restrict__ out,
                                                 const float* __restrict__ wp0,
                                                 const float* __restrict__ wp1,
                                                 const unsigned short* __restrict__ wf,
                                                 const float* __restrict__ bfc0,
                                                 uint32_t key0, uint32_t key1) {
  // 40960 B exactly = 160KiB/4 -> 4 workgroups/CU.
  __shared__ __align__(16) unsigned short s_wf[20480];

  const int tid = threadIdx.x;
  {
    const uint4* src = (const uint4*)wf;
    uint4* dst = (uint4*)s_wf;
#pragma unroll
    for (int i = 0; i < 10; i++) dst[tid + 256 * i] = src[tid + 256 * i];
  }
  __syncthreads();

  const int lane = tid & 63;
  const int h8 = (tid >> 5) & 1;
  const int ln31 = tid & 31;
  const int wv = tid >> 6;

  // No XCD swizzle (R1: 2.13x WRITE amplification). No nt stores (R5: 2.18x
  // WRITE + RMW FETCH +35MB — partial-line 16B stores need L2 write-combining).
  const int bid = blockIdx.x;
  const uint32_t wbase = ((uint32_t)bid << 8) + (uint32_t)wv * 64u;

  // ---- perception: pixel p = row-base + tid ----
  const int b = bid >> 8;
  const int h = bid & 255;
  const int w = tid;
  const int rows[3] = { (h == 0) ? 1 : h - 1, h, (h == 255) ? 254 : h + 1 };
  const int cols[3] = { (w == 0) ? 1 : w - 1, w, (w == 255) ? 254 : w + 1 };

  float perc[48];
#pragma unroll
  for (int i = 16; i < 48; i++) perc[i] = 0.f;

#pragma unroll
  for (int ty = 0; ty < 3; ty++) {
#pragma unroll
    for (int tx = 0; tx < 3; tx++) {
      const int tap = ty * 3 + tx;
      const float4* pv =
          (const float4*)(in + (size_t)(((b << 8) + rows[ty]) * 256 + cols[tx]) * 16);
#pragma unroll
      for (int q = 0; q < 4; q++) {
        float4 v = pv[q];
        float vv[4] = { v.x, v.y, v.z, v.w };
#pragma unroll
        for (int j = 0; j < 4; j++) {
          const int c = 4 * q + j;
          perc[16 + c] = fmaf(wp0[tap * 16 + c], vv[j], perc[16 + c]);
          perc[32 + c] = fmaf(wp1[tap * 16 + c], vv[j], perc[32 + c]);
          if (tap == 4) perc[c] = vv[j];
        }
      }
    }
  }

  // ---- split perc to f16 hi/lo, packed as dword pairs (k even in low half) ----
  uint32_t hi2[24], lo2[24];
#pragma unroll
  for (int q = 0; q < 24; q++) {
    const float a = perc[2 * q], bq = perc[2 * q + 1];
    const _Float16 ah = (_Float16)a, bh = (_Float16)bq;
    const _Float16 al = (_Float16)(a - (float)ah), bl = (_Float16)(bq - (float)bh);
    hi2[q] = pk2(ah, bh);
    lo2[q] = pk2(al, bl);
  }

  // ---- GEMM1 B-fragments via permlane32_swap: one op makes B0 and B1 ----
  uint32_t B0h[3][4], B0l[3][4], B1h[3][4], B1l[3][4];
#pragma unroll
  for (int kt = 0; kt < 3; kt++) {
#pragma unroll
    for (int d = 0; d < 4; d++) {
      uint32_t ah = hi2[kt * 8 + d], bh = hi2[kt * 8 + 4 + d];
      pl32swap(ah, bh);
      B0h[kt][d] = ah; B1h[kt][d] = bh;
      uint32_t al = lo2[kt * 8 + d], bl = lo2[kt * 8 + 4 + d];
      pl32swap(al, bl);
      B0l[kt][d] = al; B1l[kt][d] = bl;
    }
  }

  floatx16 g2a, g2b;
#pragma unroll
  for (int i = 0; i < 16; i++) { g2a[i] = 0.f; g2b[i] = 0.f; }

  const float4* bp = (const float4*)bfc0;  // 512 B, L1-resident

#pragma unroll
  for (int Mt = 0; Mt < 4; Mt++) {
    half8 Ah[3], Al[3];
#pragma unroll
    for (int kt = 0; kt < 3; kt++) {
      Ah[kt] = *(const half8*)&s_wf[((Mt * 3 + kt) * 2 + 0) * 512 + lane * 8];
      Al[kt] = *(const half8*)&s_wf[((Mt * 3 + kt) * 2 + 1) * 512 + lane * 8];
    }
    // bias init per D-reg r=8u+s: logical unit = 32*Mt + 16*u + 8*h8 + s
    const float4 bb0 = bp[Mt * 8 + 2 * h8];
    const float4 bb1 = bp[Mt * 8 + 2 * h8 + 1];
    const float4 bb2 = bp[Mt * 8 + 4 + 2 * h8];
    const float4 bb3 = bp[Mt * 8 + 4 + 2 * h8 + 1];
    floatx16 acc0 = { bb0.x, bb0.y, bb0.z, bb0.w, bb1.x, bb1.y, bb1.z, bb1.w,
                      bb2.x, bb2.y, bb2.z, bb2.w, bb3.x, bb3.y, bb3.z, bb3.w };
    floatx16 acc1 = acc0;

#pragma unroll
    for (int kt = 0; kt < 3; kt++) {
      const half8 b0h = mk8(B0h[kt][0], B0h[kt][1], B0h[kt][2], B0h[kt][3]);
      const half8 b0l = mk8(B0l[kt][0], B0l[kt][1], B0l[kt][2], B0l[kt][3]);
      const half8 b1h = mk8(B1h[kt][0], B1h[kt][1], B1h[kt][2], B1h[kt][3]);
      const half8 b1l = mk8(B1l[kt][0], B1l[kt][1], B1l[kt][2], B1l[kt][3]);
      acc0 = __builtin_amdgcn_mfma_f32_32x32x16_f16(Ah[kt], b0h, acc0, 0, 0, 0);
      acc0 = __builtin_amdgcn_mfma_f32_32x32x16_f16(Al[kt], b0h, acc0, 0, 0, 0);
      acc0 = __builtin_amdgcn_mfma_f32_32x32x16_f16(Ah[kt], b0l, acc0, 0, 0, 0);
      acc1 = __builtin_amdgcn_mfma_f32_32x32x16_f16(Ah[kt], b1h, acc1, 0, 0, 0);
      acc1 = __builtin_amdgcn_mfma_f32_32x32x16_f16(Al[kt], b1h, acc1, 0, 0, 0);
      acc1 = __builtin_amdgcn_mfma_f32_32x32x16_f16(Ah[kt], b1l, acc1, 0, 0, 0);
    }

    // ---- H-transform + GEMM2: acc reg 8u+s holds the logical unit for
    // B2 k-slot s (thanks to the W0 permutation) -> no shuffles, no selects.
#pragma unroll
    for (int u = 0; u < 2; u++) {
      const int kt2 = 2 * Mt + u;
      const half8 W1h = *(const half8*)&s_wf[12288 + (kt2 * 2 + 0) * 512 + lane * 8];
      const half8 W1l = *(const half8*)&s_wf[12288 + (kt2 * 2 + 1) * 512 + lane * 8];
#pragma unroll
      for (int nt = 0; nt < 2; nt++) {
        float hv[8];
#pragma unroll
        for (int s = 0; s < 8; s++) {
          const float v = nt ? acc1[8 * u + s] : acc0[8 * u + s];
          hv[s] = fmaxf(v, 0.f);
        }
        uint32_t pkh[4], pkl[4];
#pragma unroll
        for (int d = 0; d < 4; d++) {
          const float a = hv[2 * d], bq = hv[2 * d + 1];
          const _Float16 ah = (_Float16)a, bh = (_Float16)bq;
          const _Float16 al = (_Float16)(a - (float)ah), bl = (_Float16)(bq - (float)bh);
          pkh[d] = pk2(ah, bh);
          pkl[d] = pk2(al, bl);
        }
        const half8 Bh2 = mk8(pkh[0], pkh[1], pkh[2], pkh[3]);
        const half8 Bl2 = mk8(pkl[0], pkl[1], pkl[2], pkl[3]);
        if (nt == 0) {
          g2a = __builtin_amdgcn_mfma_f32_32x32x16_f16(W1h, Bh2, g2a, 0, 0, 0);
          g2a = __builtin_amdgcn_mfma_f32_32x32x16_f16(W1l, Bh2, g2a, 0, 0, 0);
          g2a = __builtin_amdgcn_mfma_f32_32x32x16_f16(W1h, Bl2, g2a, 0, 0, 0);
        } else {
          g2b = __builtin_amdgcn_mfma_f32_32x32x16_f16(W1h, Bh2, g2b, 0, 0, 0);
          g2b = __builtin_amdgcn_mfma_f32_32x32x16_f16(W1l, Bh2, g2b, 0, 0, 0);
          g2b = __builtin_amdgcn_mfma_f32_32x32x16_f16(W1h, Bl2, g2b, 0, 0, 0);
        }
      }
    }
  }

  // ---- epilogue: h8=0 regs = ch 3..7; h8=1 regs = ch 8..15. No shuffles.
#pragma unroll
  for (int nt = 0; nt < 2; nt++) {
    float dxv[8];
#pragma unroll
    for (int i = 0; i < 8; i++) dxv[i] = nt ? g2b[i] : g2a[i];
    const uint32_t p = wbase + (uint32_t)(nt * 32) + (uint32_t)ln31;
    uint32_t t0, t1;
    threefry2x32(key0, key1, 0u, p, t0, t1);
    const uint32_t bits = t0 ^ t1;
    const float uu = __uint_as_float((bits >> 9) | 0x3f800000u) - 1.0f;
    const float M = (uu <= 0.5f) ? 1.f : 0.f;
    const float4* sp = (const float4*)(in + (size_t)p * 16);
    const float4 sA = sp[2 * h8];
    const float4 sB = sp[2 * h8 + 1];
    float4 oA, oB;
    oA.x = h8 ? fmaf(M, dxv[0], sA.x) : sA.x;                  // ch8  | ch0
    oA.y = h8 ? fmaf(M, dxv[1], sA.y) : sA.y;                  // ch9  | ch1
    oA.z = h8 ? fmaf(M, dxv[2], sA.z) : sA.z;                  // ch10 | ch2
    oA.w = fmaf(M, h8 ? dxv[3] : dxv[0], sA.w);                // ch11 | ch3
    oB.x = fmaf(M, h8 ? dxv[4] : dxv[1], sB.x);                // ch12 | ch4
    oB.y = fmaf(M, h8 ? dxv[5] : dxv[2], sB.y);                // ch13 | ch5
    oB.z = fmaf(M, h8 ? dxv[6] : dxv[3], sB.z);                // ch14 | ch6
    oB.w = fmaf(M, h8 ? dxv[7] : dxv[4], sB.w);                // ch15 | ch7
    float4* dp = (float4*)(out + (size_t)p * 16);
    dp[2 * h8] = oA;
    dp[2 * h8 + 1] = oB;
  }
}

// ---------------- NHWC state -> (out slice, x_final NCHW) ----------------
__global__ __launch_bounds__(256) void k_nhwc_to_out(const float* __restrict__ st,
                                                     float* __restrict__ outp) {
  const int p = blockIdx.x * 256 + threadIdx.x;
  const int b = p >> 16;
  const int hw = p & 65535;
  const float4* src = (const float4*)(st + (size_t)p * 16);
  float v[16];
#pragma unroll
  for (int q = 0; q < 4; q++) {
    float4 t = src[q];
    v[4 * q] = t.x; v[4 * q + 1] = t.y; v[4 * q + 2] = t.z; v[4 * q + 3] = t.w;
  }
  float* xf = outp + NPIX;  // x_final region of d_out
#pragma unroll
  for (int c = 0; c < 16; c++) xf[(size_t)(b * 16 + c) * HW + hw] = v[c];
  outp[(size_t)b * HW + hw] = v[3];  // out = x_final[:, 3:4]
}

extern "C" void kernel_launch(void* const* d_in, const int* in_sizes, int n_in,
                              void* d_out, int out_size, void* d_ws, size_t ws_size,
                              hipStream_t stream) {
  const float* x    = (const float*)d_in[0];
  const float* wp0  = (const float*)d_in[1];
  const float* wp1  = (const float*)d_in[2];
  const float* wfc0 = (const float*)d_in[3];
  const float* bfc0 = (const float*)d_in[4];
  const float* wfc1 = (const float*)d_in[5];
  float* out = (float*)d_out;

  unsigned short* wf = (unsigned short*)d_ws;          // 20480 f16 (40960 B)
  float* S0 = (float*)((char*)d_ws + 65536);           // 33.5 MB scratch state
  float* S1 = out + NPIX;                              // x_final region as scratch

  // Step keys: foldlike split of key(42): keys[s] = threefry((0,42),(0,s))
  uint32_t k0[NSTEPS], k1[NSTEPS];
  for (int s = 0; s < NSTEPS; s++)
    threefry2x32(0u, 42u, 0u, (uint32_t)s, k0[s], k1[s]);

  dim3 block(256);
  hipLaunchKernelGGL(k_prep, dim3(80), block, 0, stream, wfc0, wfc1, wf);
  hipLaunchKernelGGL(k_nchw_to_nhwc, dim3(NPIX / 256), block, 0, stream, x, S0);
  float* cur = S0;
  float* nxt = S1;
  for (int s = 0; s < NSTEPS; s++) {
    hipLaunchKernelGGL(k_step, dim3(Bn * Hh), block, 0, stream,
                       cur, nxt, wp0, wp1, wf, bfc0, k0[s], k1[s]);
    float* t = cur; cur = nxt; nxt = t;
  }
  // 32 steps (even) -> final state back in S0
  hipLaunchKernelGGL(k_nhwc_to_out, dim3(NPIX / 256), block, 0, stream, cur, out);
}

// Round 14
// 1815.873 us; speedup vs baseline: 1.1226x; 1.1226x over previous
//
#include <hip/hip_runtime.h>
#include <stdint.h>

#define Cc   16
#define HIDD 128
#define Bn   8
#define Hh   256
#define Ww   256
#define HW   (Hh * Ww)         // 65536
#define NPIX (Bn * HW)         // 524288
#define NSTEPS 32

typedef _Float16 half8 __attribute__((ext_vector_type(8)));
typedef float floatx16 __attribute__((ext_vector_type(16)));

// ---------------- JAX threefry2x32 (20 rounds), host+device ----------------
__host__ __device__ inline void threefry2x32(uint32_t k1, uint32_t k2,
                                             uint32_t x0, uint32_t x1,
                                             uint32_t& o0, uint32_t& o1) {
  const uint32_t ks2 = k1 ^ k2 ^ 0x1BD11BDAu;
  uint32_t v0 = x0 + k1;
  uint32_t v1 = x1 + k2;
#define ROTL32(x, n) (((x) << (n)) | ((x) >> (32 - (n))))
#define R4(a, b, c, d)                                    \
  { v0 += v1; v1 = ROTL32(v1, a); v1 ^= v0;               \
    v0 += v1; v1 = ROTL32(v1, b); v1 ^= v0;               \
    v0 += v1; v1 = ROTL32(v1, c); v1 ^= v0;               \
    v0 += v1; v1 = ROTL32(v1, d); v1 ^= v0; }
  R4(13, 15, 26, 6)   v0 += k2;  v1 += ks2 + 1u;
  R4(17, 29, 16, 24)  v0 += ks2; v1 += k1 + 2u;
  R4(13, 15, 26, 6)   v0 += k1;  v1 += k2 + 3u;
  R4(17, 29, 16, 24)  v0 += k2;  v1 += ks2 + 4u;
  R4(13, 15, 26, 6)   v0 += ks2; v1 += k1 + 5u;
#undef R4
#undef ROTL32
  o0 = v0;
  o1 = v1;
}

__device__ inline uint32_t pk2(_Float16 a, _Float16 b) {
  union { _Float16 h[2]; uint32_t u; } t;
  t.h[0] = a; t.h[1] = b;
  return t.u;
}
__device__ inline half8 mk8(uint32_t a, uint32_t b, uint32_t c, uint32_t d) {
  union { uint32_t u[4]; half8 h; } t;
  t.u[0] = a; t.u[1] = b; t.u[2] = c; t.u[3] = d;
  return t.h;
}

// v_permlane32_swap_b32: a.lanes[32:63] <-> b.lanes[0:31] (both regs updated).
__device__ inline void pl32swap(uint32_t& a, uint32_t& b) {
  asm("v_permlane32_swap_b32 %0, %1" : "+v"(a), "+v"(b));
}

// ---- prep: pack W0^T / W1p^T into 32x32x16 A-fragment order (f16 hi/lo) ----
// Hidden units are PERMUTED so GEMM1's D-register layout row=(r&3)+8*(r>>2)+4*h8
// lines up with GEMM2's B k-slot layout k=8*h8+j (bit-exact relabeling).
// W1's M rows permuted so each half-wave holds exactly the 8 channels it stores.
__global__ __launch_bounds__(256) void k_prep(const float* __restrict__ wfc0,
                                              const float* __restrict__ wfc1,
                                              unsigned short* __restrict__ wf) {
  const int idx = blockIdx.x * 256 + threadIdx.x;
  if (idx < 12288) {
    const int j = idx & 7;
    const int t = idx >> 3;
    const int lane = t & 63;
    const int t2 = t >> 6;
    const int spl = t2 & 1;
    const int fk = t2 >> 1;
    const int kt = fk % 3;
    const int Mt = fk / 3;
    const int rho = lane & 31;
    const int r16 = rho & 15;
    const int mlog = Mt * 32 + (rho >> 4) * 16
                   + ((r16 >> 2) & 1) * 8 + ((r16 >> 3) & 1) * 4 + (r16 & 3);
    const int k = kt * 16 + (lane >> 5) * 8 + j;
    const float v = wfc0[k * HIDD + mlog];
    const _Float16 hi = (_Float16)v;
    const _Float16 r = spl ? (_Float16)(v - (float)hi) : hi;
    union { _Float16 h; unsigned short s; } cv; cv.h = r;
    wf[idx] = cv.s;
  } else if (idx < 20480) {
    const int idx2 = idx - 12288;
    const int j = idx2 & 7;
    const int t = idx2 >> 3;
    const int lane = t & 63;
    const int t2 = t >> 6;
    const int spl = t2 & 1;
    const int kt2 = t2 >> 1;
    const int rho = lane & 31;
    int ml = -1;                       // dx channel = ml+3
    if (rho < 4) ml = rho;             // phys 0..3  -> ch 3..6   (h8=0 r0..3)
    else if (rho < 8) ml = rho + 1;    // phys 4..7  -> ch 8..11  (h8=1 r0..3)
    else if (rho == 8) ml = 4;         // phys 8     -> ch 7      (h8=0 r4)
    else if (rho >= 12 && rho < 16) ml = rho - 3;  // phys 12..15 -> ch 12..15
    const int k = kt2 * 16 + (lane >> 5) * 8 + j;  // logical hid (unchanged)
    const float v = (ml >= 0) ? wfc1[k * 16 + (ml + 3)] : 0.f;
    const _Float16 hi = (_Float16)v;
    const _Float16 r = spl ? (_Float16)(v - (float)hi) : hi;
    union { _Float16 h; unsigned short s; } cv; cv.h = r;
    wf[idx] = cv.s;
  }
}

// ---------------- NCHW -> NHWC state init ----------------
__global__ __launch_bounds__(256) void k_nchw_to_nhwc(const float* __restrict__ x,
                                                      float* __restrict__ st) {
  const int p = blockIdx.x * 256 + threadIdx.x;
  const int b = p >> 16;
  const int hw = p & 65535;
  const float* src = x + (size_t)b * (Cc * HW) + hw;
  float v[16];
#pragma unroll
  for (int c = 0; c < 16; c++) v[c] = src[(size_t)c * HW];
  float4* dst = (float4*)(st + (size_t)p * 16);
#pragma unroll
  for (int q = 0; q < 4; q++)
    dst[q] = make_float4(v[4 * q], v[4 * q + 1], v[4 * q + 2], v[4 * q + 3]);
}

// ---------------- One NCA step: perception (VALU) + MLP (MFMA) ----------------
__global__ __launch_bounds__(256, 4) void k_step(const float* __restrict__ in,
                                                 float* __restrict__ out,
                                                 const float* __restrict__ wp0,
                                                 const float* __restrict__ wp1,
                                                 const unsigned short* __restrict__ wf,
                                                 const float* __restrict__ bfc0,
                                                 uint32_t key0, uint32_t key1) {
  // LDS padded to 41472 B -> 3 WG/CU (measured R0 vs R1/R5/R6: 4 WG/CU
  // amplifies WRITE_SIZE 2.13x (32768->69632 KiB) + FETCH +34MB via L2
  // thrash; 3 WG/CU keeps WRITE exactly 32 MiB and total traffic ~85MB/step).
  __shared__ __align__(16) unsigned short s_wf[20736];

  const int tid = threadIdx.x;
  {
    const uint4* src = (const uint4*)wf;
    uint4* dst = (uint4*)s_wf;
#pragma unroll
    for (int i = 0; i < 10; i++) dst[tid + 256 * i] = src[tid + 256 * i];
  }
  __syncthreads();

  const int lane = tid & 63;
  const int h8 = (tid >> 5) & 1;
  const int ln31 = tid & 31;
  const int wv = tid >> 6;

  const int bid = blockIdx.x;
  const uint32_t wbase = ((uint32_t)bid << 8) + (uint32_t)wv * 64u;

  // ---- perception: pixel p = row-base + tid ----
  const int b = bid >> 8;
  const int h = bid & 255;
  const int w = tid;
  const int rows[3] = { (h == 0) ? 1 : h - 1, h, (h == 255) ? 254 : h + 1 };
  const int cols[3] = { (w == 0) ? 1 : w - 1, w, (w == 255) ? 254 : w + 1 };

  float perc[48];
#pragma unroll
  for (int i = 16; i < 48; i++) perc[i] = 0.f;

#pragma unroll
  for (int ty = 0; ty < 3; ty++) {
#pragma unroll
    for (int tx = 0; tx < 3; tx++) {
      const int tap = ty * 3 + tx;
      const float4* pv =
          (const float4*)(in + (size_t)(((b << 8) + rows[ty]) * 256 + cols[tx]) * 16);
#pragma unroll
      for (int q = 0; q < 4; q++) {
        float4 v = pv[q];
        float vv[4] = { v.x, v.y, v.z, v.w };
#pragma unroll
        for (int j = 0; j < 4; j++) {
          const int c = 4 * q + j;
          perc[16 + c] = fmaf(wp0[tap * 16 + c], vv[j], perc[16 + c]);
          perc[32 + c] = fmaf(wp1[tap * 16 + c], vv[j], perc[32 + c]);
          if (tap == 4) perc[c] = vv[j];
        }
      }
    }
  }

  // ---- split perc to f16 hi/lo, packed as dword pairs (k even in low half) ----
  uint32_t hi2[24], lo2[24];
#pragma unroll
  for (int q = 0; q < 24; q++) {
    const float a = perc[2 * q], bq = perc[2 * q + 1];
    const _Float16 ah = (_Float16)a, bh = (_Float16)bq;
    const _Float16 al = (_Float16)(a - (float)ah), bl = (_Float16)(bq - (float)bh);
    hi2[q] = pk2(ah, bh);
    lo2[q] = pk2(al, bl);
  }

  // ---- GEMM1 B-fragments via permlane32_swap: one op makes B0 and B1 ----
  uint32_t B0h[3][4], B0l[3][4], B1h[3][4], B1l[3][4];
#pragma unroll
  for (int kt = 0; kt < 3; kt++) {
#pragma unroll
    for (int d = 0; d < 4; d++) {
      uint32_t ah = hi2[kt * 8 + d], bh = hi2[kt * 8 + 4 + d];
      pl32swap(ah, bh);
      B0h[kt][d] = ah; B1h[kt][d] = bh;
      uint32_t al = lo2[kt * 8 + d], bl = lo2[kt * 8 + 4 + d];
      pl32swap(al, bl);
      B0l[kt][d] = al; B1l[kt][d] = bl;
    }
  }

  floatx16 g2a, g2b;
#pragma unroll
  for (int i = 0; i < 16; i++) { g2a[i] = 0.f; g2b[i] = 0.f; }

  const float4* bp = (const float4*)bfc0;  // 512 B, L1-resident

#pragma unroll
  for (int Mt = 0; Mt < 4; Mt++) {
    half8 Ah[3], Al[3];
#pragma unroll
    for (int kt = 0; kt < 3; kt++) {
      Ah[kt] = *(const half8*)&s_wf[((Mt * 3 + kt) * 2 + 0) * 512 + lane * 8];
      Al[kt] = *(const half8*)&s_wf[((Mt * 3 + kt) * 2 + 1) * 512 + lane * 8];
    }
    // bias init per D-reg r=8u+s: logical unit = 32*Mt + 16*u + 8*h8 + s
    const float4 bb0 = bp[Mt * 8 + 2 * h8];
    const float4 bb1 = bp[Mt * 8 + 2 * h8 + 1];
    const float4 bb2 = bp[Mt * 8 + 4 + 2 * h8];
    const float4 bb3 = bp[Mt * 8 + 4 + 2 * h8 + 1];
    floatx16 acc0 = { bb0.x, bb0.y, bb0.z, bb0.w, bb1.x, bb1.y, bb1.z, bb1.w,
                      bb2.x, bb2.y, bb2.z, bb2.w, bb3.x, bb3.y, bb3.z, bb3.w };
    floatx16 acc1 = acc0;

#pragma unroll
    for (int kt = 0; kt < 3; kt++) {
      const half8 b0h = mk8(B0h[kt][0], B0h[kt][1], B0h[kt][2], B0h[kt][3]);
      const half8 b0l = mk8(B0l[kt][0], B0l[kt][1], B0l[kt][2], B0l[kt][3]);
      const half8 b1h = mk8(B1h[kt][0], B1h[kt][1], B1h[kt][2], B1h[kt][3]);
      const half8 b1l = mk8(B1l[kt][0], B1l[kt][1], B1l[kt][2], B1l[kt][3]);
      acc0 = __builtin_amdgcn_mfma_f32_32x32x16_f16(Ah[kt], b0h, acc0, 0, 0, 0);
      acc0 = __builtin_amdgcn_mfma_f32_32x32x16_f16(Al[kt], b0h, acc0, 0, 0, 0);
      acc0 = __builtin_amdgcn_mfma_f32_32x32x16_f16(Ah[kt], b0l, acc0, 0, 0, 0);
      acc1 = __builtin_amdgcn_mfma_f32_32x32x16_f16(Ah[kt], b1h, acc1, 0, 0, 0);
      acc1 = __builtin_amdgcn_mfma_f32_32x32x16_f16(Al[kt], b1h, acc1, 0, 0, 0);
      acc1 = __builtin_amdgcn_mfma_f32_32x32x16_f16(Ah[kt], b1l, acc1, 0, 0, 0);
    }

    // ---- H-transform + GEMM2: acc reg 8u+s holds the logical unit for
    // B2 k-slot s (thanks to the W0 permutation) -> no shuffles, no selects.
#pragma unroll
    for (int u = 0; u < 2; u++) {
      const int kt2 = 2 * Mt + u;
      const half8 W1h = *(const half8*)&s_wf[12288 + (kt2 * 2 + 0) * 512 + lane * 8];
      const half8 W1l = *(const half8*)&s_wf[12288 + (kt2 * 2 + 1) * 512 + lane * 8];
#pragma unroll
      for (int nt = 0; nt < 2; nt++) {
        float hv[8];
#pragma unroll
        for (int s = 0; s < 8; s++) {
          const float v = nt ? acc1[8 * u + s] : acc0[8 * u + s];
          hv[s] = fmaxf(v, 0.f);
        }
        uint32_t pkh[4], pkl[4];
#pragma unroll
        for (int d = 0; d < 4; d++) {
          const float a = hv[2 * d], bq = hv[2 * d + 1];
          const _Float16 ah = (_Float16)a, bh = (_Float16)bq;
          const _Float16 al = (_Float16)(a - (float)ah), bl = (_Float16)(bq - (float)bh);
          pkh[d] = pk2(ah, bh);
          pkl[d] = pk2(al, bl);
        }
        const half8 Bh2 = mk8(pkh[0], pkh[1], pkh[2], pkh[3]);
        const half8 Bl2 = mk8(pkl[0], pkl[1], pkl[2], pkl[3]);
        if (nt == 0) {
          g2a = __builtin_amdgcn_mfma_f32_32x32x16_f16(W1h, Bh2, g2a, 0, 0, 0);
          g2a = __builtin_amdgcn_mfma_f32_32x32x16_f16(W1l, Bh2, g2a, 0, 0, 0);
          g2a = __builtin_amdgcn_mfma_f32_32x32x16_f16(W1h, Bl2, g2a, 0, 0, 0);
        } else {
          g2b = __builtin_amdgcn_mfma_f32_32x32x16_f16(W1h, Bh2, g2b, 0, 0, 0);
          g2b = __builtin_amdgcn_mfma_f32_32x32x16_f16(W1l, Bh2, g2b, 0, 0, 0);
          g2b = __builtin_amdgcn_mfma_f32_32x32x16_f16(W1h, Bl2, g2b, 0, 0, 0);
        }
      }
    }
  }

  // ---- epilogue: h8=0 regs = ch 3..7; h8=1 regs = ch 8..15. No shuffles.
#pragma unroll
  for (int nt = 0; nt < 2; nt++) {
    float dxv[8];
#pragma unroll
    for (int i = 0; i < 8; i++) dxv[i] = nt ? g2b[i] : g2a[i];
    const uint32_t p = wbase + (uint32_t)(nt * 32) + (uint32_t)ln31;
    uint32_t t0, t1;
    threefry2x32(key0, key1, 0u, p, t0, t1);
    const uint32_t bits = t0 ^ t1;
    const float uu = __uint_as_float((bits >> 9) | 0x3f800000u) - 1.0f;
    const float M = (uu <= 0.5f) ? 1.f : 0.f;
    const float4* sp = (const float4*)(in + (size_t)p * 16);
    const float4 sA = sp[2 * h8];
    const float4 sB = sp[2 * h8 + 1];
    float4 oA, oB;
    oA.x = h8 ? fmaf(M, dxv[0], sA.x) : sA.x;                  // ch8  | ch0
    oA.y = h8 ? fmaf(M, dxv[1], sA.y) : sA.y;                  // ch9  | ch1
    oA.z = h8 ? fmaf(M, dxv[2], sA.z) : sA.z;                  // ch10 | ch2
    oA.w = fmaf(M, h8 ? dxv[3] : dxv[0], sA.w);                // ch11 | ch3
    oB.x = fmaf(M, h8 ? dxv[4] : dxv[1], sB.x);                // ch12 | ch4
    oB.y = fmaf(M, h8 ? dxv[5] : dxv[2], sB.y);                // ch13 | ch5
    oB.z = fmaf(M, h8 ? dxv[6] : dxv[3], sB.z);                // ch14 | ch6
    oB.w = fmaf(M, h8 ? dxv[7] : dxv[4], sB.w);                // ch15 | ch7
    float4* dp = (float4*)(out + (size_t)p * 16);
    dp[2 * h8] = oA;
    dp[2 * h8 + 1] = oB;
  }
}

// ---------------- NHWC state -> (out slice, x_final NCHW) ----------------
__global__ __launch_bounds__(256) void k_nhwc_to_out(const float* __restrict__ st,
                                                     float* __restrict__ outp) {
  const int p = blockIdx.x * 256 + threadIdx.x;
  const int b = p >> 16;
  const int hw = p & 65535;
  const float4* src = (const float4*)(st + (size_t)p * 16);
  float v[16];
#pragma unroll
  for (int q = 0; q < 4; q++) {
    float4 t = src[q];
    v[4 * q] = t.x; v[4 * q + 1] = t.y; v[4 * q + 2] = t.z; v[4 * q + 3] = t.w;
  }
  float* xf = outp + NPIX;  // x_final region of d_out
#pragma unroll
  for (int c = 0; c < 16; c++) xf[(size_t)(b * 16 + c) * HW + hw] = v[c];
  outp[(size_t)b * HW + hw] = v[3];  // out = x_final[:, 3:4]
}

extern "C" void kernel_launch(void* const* d_in, const int* in_sizes, int n_in,
                              void* d_out, int out_size, void* d_ws, size_t ws_size,
                              hipStream_t stream) {
  const float* x    = (const float*)d_in[0];
  const float* wp0  = (const float*)d_in[1];
  const float* wp1  = (const float*)d_in[2];
  const float* wfc0 = (const float*)d_in[3];
  const float* bfc0 = (const float*)d_in[4];
  const float* wfc1 = (const float*)d_in[5];
  float* out = (float*)d_out;

  unsigned short* wf = (unsigned short*)d_ws;          // 20480 f16 (40960 B)
  float* S0 = (float*)((char*)d_ws + 65536);           // 33.5 MB scratch state
  float* S1 = out + NPIX;                              // x_final region as scratch

  // Step keys: foldlike split of key(42): keys[s] = threefry((0,42),(0,s))
  uint32_t k0[NSTEPS], k1[NSTEPS];
  for (int s = 0; s < NSTEPS; s++)
    threefry2x32(0u, 42u, 0u, (uint32_t)s, k0[s], k1[s]);

  dim3 block(256);
  hipLaunchKernelGGL(k_prep, dim3(80), block, 0, stream, wfc0, wfc1, wf);
  hipLaunchKernelGGL(k_nchw_to_nhwc, dim3(NPIX / 256), block, 0, stream, x, S0);
  float* cur = S0;
  float* nxt = S1;
  for (int s = 0; s < NSTEPS; s++) {
    hipLaunchKernelGGL(k_step, dim3(Bn * Hh), block, 0, stream,
                       cur, nxt, wp0, wp1, wf, bfc0, k0[s], k1[s]);
    float* t = cur; cur = nxt; nxt = t;
  }
  // 32 steps (even) -> final state back in S0
  hipLaunchKernelGGL(k_nhwc_to_out, dim3(NPIX / 256), block, 0, stream, cur, out);
}

// Round 15
// 1749.844 us; speedup vs baseline: 1.1650x; 1.0377x over previous
//
#include <hip/hip_runtime.h>
#include <stdint.h>

#define Cc   16
#define HIDD 128
#define Bn   8
#define Hh   256
#define Ww   256
#define HW   (Hh * Ww)         // 65536
#define NPIX (Bn * HW)         // 524288
#define NSTEPS 32

typedef _Float16 half8 __attribute__((ext_vector_type(8)));
typedef float floatx16 __attribute__((ext_vector_type(16)));

// ---------------- JAX threefry2x32 (20 rounds), host+device ----------------
__host__ __device__ inline void threefry2x32(uint32_t k1, uint32_t k2,
                                             uint32_t x0, uint32_t x1,
                                             uint32_t& o0, uint32_t& o1) {
  const uint32_t ks2 = k1 ^ k2 ^ 0x1BD11BDAu;
  uint32_t v0 = x0 + k1;
  uint32_t v1 = x1 + k2;
#define ROTL32(x, n) (((x) << (n)) | ((x) >> (32 - (n))))
#define R4(a, b, c, d)                                    \
  { v0 += v1; v1 = ROTL32(v1, a); v1 ^= v0;               \
    v0 += v1; v1 = ROTL32(v1, b); v1 ^= v0;               \
    v0 += v1; v1 = ROTL32(v1, c); v1 ^= v0;               \
    v0 += v1; v1 = ROTL32(v1, d); v1 ^= v0; }
  R4(13, 15, 26, 6)   v0 += k2;  v1 += ks2 + 1u;
  R4(17, 29, 16, 24)  v0 += ks2; v1 += k1 + 2u;
  R4(13, 15, 26, 6)   v0 += k1;  v1 += k2 + 3u;
  R4(17, 29, 16, 24)  v0 += k2;  v1 += ks2 + 4u;
  R4(13, 15, 26, 6)   v0 += ks2; v1 += k1 + 5u;
#undef R4
#undef ROTL32
  o0 = v0;
  o1 = v1;
}

__device__ inline uint32_t pk2(_Float16 a, _Float16 b) {
  union { _Float16 h[2]; uint32_t u; } t;
  t.h[0] = a; t.h[1] = b;
  return t.u;
}
__device__ inline half8 mk8(uint32_t a, uint32_t b, uint32_t c, uint32_t d) {
  union { uint32_t u[4]; half8 h; } t;
  t.u[0] = a; t.u[1] = b; t.u[2] = c; t.u[3] = d;
  return t.h;
}

// v_permlane32_swap_b32: a.lanes[32:63] <-> b.lanes[0:31] (both regs updated).
__device__ inline void pl32swap(uint32_t& a, uint32_t& b) {
  asm("v_permlane32_swap_b32 %0, %1" : "+v"(a), "+v"(b));
}

// ---- prep: pack W0^T / W1p^T into 32x32x16 A-fragment order (f16 hi/lo) ----
// Hidden units are PERMUTED so GEMM1's D-register layout row=(r&3)+8*(r>>2)+4*h8
// lines up with GEMM2's B k-slot layout k=8*h8+j (bit-exact relabeling).
// W1's M rows permuted so each half-wave holds exactly the 8 channels it stores.
__global__ __launch_bounds__(256) void k_prep(const float* __restrict__ wfc0,
                                              const float* __restrict__ wfc1,
                                              unsigned short* __restrict__ wf) {
  const int idx = blockIdx.x * 256 + threadIdx.x;
  if (idx < 12288) {
    const int j = idx & 7;
    const int t = idx >> 3;
    const int lane = t & 63;
    const int t2 = t >> 6;
    const int spl = t2 & 1;
    const int fk = t2 >> 1;
    const int kt = fk % 3;
    const int Mt = fk / 3;
    const int rho = lane & 31;
    const int r16 = rho & 15;
    const int mlog = Mt * 32 + (rho >> 4) * 16
                   + ((r16 >> 2) & 1) * 8 + ((r16 >> 3) & 1) * 4 + (r16 & 3);
    const int k = kt * 16 + (lane >> 5) * 8 + j;
    const float v = wfc0[k * HIDD + mlog];
    const _Float16 hi = (_Float16)v;
    const _Float16 r = spl ? (_Float16)(v - (float)hi) : hi;
    union { _Float16 h; unsigned short s; } cv; cv.h = r;
    wf[idx] = cv.s;
  } else if (idx < 20480) {
    const int idx2 = idx - 12288;
    const int j = idx2 & 7;
    const int t = idx2 >> 3;
    const int lane = t & 63;
    const int t2 = t >> 6;
    const int spl = t2 & 1;
    const int kt2 = t2 >> 1;
    const int rho = lane & 31;
    int ml = -1;                       // dx channel = ml+3
    if (rho < 4) ml = rho;             // phys 0..3  -> ch 3..6   (h8=0 r0..3)
    else if (rho < 8) ml = rho + 1;    // phys 4..7  -> ch 8..11  (h8=1 r0..3)
    else if (rho == 8) ml = 4;         // phys 8     -> ch 7      (h8=0 r4)
    else if (rho >= 12 && rho < 16) ml = rho - 3;  // phys 12..15 -> ch 12..15
    const int k = kt2 * 16 + (lane >> 5) * 8 + j;  // logical hid (unchanged)
    const float v = (ml >= 0) ? wfc1[k * 16 + (ml + 3)] : 0.f;
    const _Float16 hi = (_Float16)v;
    const _Float16 r = spl ? (_Float16)(v - (float)hi) : hi;
    union { _Float16 h; unsigned short s; } cv; cv.h = r;
    wf[idx] = cv.s;
  }
}

// ---------------- NCHW -> NHWC state init ----------------
__global__ __launch_bounds__(256) void k_nchw_to_nhwc(const float* __restrict__ x,
                                                      float* __restrict__ st) {
  const int p = blockIdx.x * 256 + threadIdx.x;
  const int b = p >> 16;
  const int hw = p & 65535;
  const float* src = x + (size_t)b * (Cc * HW) + hw;
  float v[16];
#pragma unroll
  for (int c = 0; c < 16; c++) v[c] = src[(size_t)c * HW];
  float4* dst = (float4*)(st + (size_t)p * 16);
#pragma unroll
  for (int q = 0; q < 4; q++)
    dst[q] = make_float4(v[4 * q], v[4 * q + 1], v[4 * q + 2], v[4 * q + 3]);
}

// ---------------- One NCA step: perception (VALU) + MLP (MFMA) ----------------
__global__ __launch_bounds__(256, 4) void k_step(const float* __restrict__ in,
                                                 float* __restrict__ out,
                                                 const float* __restrict__ wp0,
                                                 const float* __restrict__ wp1,
                                                 const unsigned short* __restrict__ wf,
                                                 const float* __restrict__ bfc0,
                                                 uint32_t key0, uint32_t key1) {
  // LDS padded to 41472 B -> 3 WG/CU (measured R0 vs R1/R5/R6 vs R14: 4 WG/CU
  // amplifies WRITE_SIZE 2.13x via L2 thrash; 3 WG/CU keeps WRITE exactly 32 MiB).
  __shared__ __align__(16) unsigned short s_wf[20736];

  const int tid = threadIdx.x;
  {
    const uint4* src = (const uint4*)wf;
    uint4* dst = (uint4*)s_wf;
#pragma unroll
    for (int i = 0; i < 10; i++) dst[tid + 256 * i] = src[tid + 256 * i];
  }
  __syncthreads();

  const int lane = tid & 63;
  const int h8 = (tid >> 5) & 1;
  const int ln31 = tid & 31;
  const int wv = tid >> 6;

  // XCD swizzle AT 3 WG/CU: XCD x owns image x; the concurrent per-XCD window
  // (~96 rows: 1.6MB reads + 1.5MB writes + 40KB weights ~ 3.1MB) fits the 4MB
  // L2, so halo rows become same-XCD L2 hits. R1 proved the FETCH benefit at
  // equal occupancy (48.7 vs 84.7 MB); R14 proved 3WG avoids the write thrash.
  // Bijective: 2048 % 8 == 0. Bit-exact (block relabeling only).
  const int bid = ((blockIdx.x & 7) << 8) | ((int)blockIdx.x >> 3);
  const uint32_t wbase = ((uint32_t)bid << 8) + (uint32_t)wv * 64u;

  // ---- perception: pixel p = row-base + tid ----
  const int b = bid >> 8;
  const int h = bid & 255;
  const int w = tid;
  const int rows[3] = { (h == 0) ? 1 : h - 1, h, (h == 255) ? 254 : h + 1 };
  const int cols[3] = { (w == 0) ? 1 : w - 1, w, (w == 255) ? 254 : w + 1 };

  float perc[48];
#pragma unroll
  for (int i = 16; i < 48; i++) perc[i] = 0.f;

#pragma unroll
  for (int ty = 0; ty < 3; ty++) {
#pragma unroll
    for (int tx = 0; tx < 3; tx++) {
      const int tap = ty * 3 + tx;
      const float4* pv =
          (const float4*)(in + (size_t)(((b << 8) + rows[ty]) * 256 + cols[tx]) * 16);
#pragma unroll
      for (int q = 0; q < 4; q++) {
        float4 v = pv[q];
        float vv[4] = { v.x, v.y, v.z, v.w };
#pragma unroll
        for (int j = 0; j < 4; j++) {
          const int c = 4 * q + j;
          perc[16 + c] = fmaf(wp0[tap * 16 + c], vv[j], perc[16 + c]);
          perc[32 + c] = fmaf(wp1[tap * 16 + c], vv[j], perc[32 + c]);
          if (tap == 4) perc[c] = vv[j];
        }
      }
    }
  }

  // ---- split perc to f16 hi/lo, packed as dword pairs (k even in low half) ----
  uint32_t hi2[24], lo2[24];
#pragma unroll
  for (int q = 0; q < 24; q++) {
    const float a = perc[2 * q], bq = perc[2 * q + 1];
    const _Float16 ah = (_Float16)a, bh = (_Float16)bq;
    const _Float16 al = (_Float16)(a - (float)ah), bl = (_Float16)(bq - (float)bh);
    hi2[q] = pk2(ah, bh);
    lo2[q] = pk2(al, bl);
  }

  // ---- GEMM1 B-fragments via permlane32_swap: one op makes B0 and B1 ----
  uint32_t B0h[3][4], B0l[3][4], B1h[3][4], B1l[3][4];
#pragma unroll
  for (int kt = 0; kt < 3; kt++) {
#pragma unroll
    for (int d = 0; d < 4; d++) {
      uint32_t ah = hi2[kt * 8 + d], bh = hi2[kt * 8 + 4 + d];
      pl32swap(ah, bh);
      B0h[kt][d] = ah; B1h[kt][d] = bh;
      uint32_t al = lo2[kt * 8 + d], bl = lo2[kt * 8 + 4 + d];
      pl32swap(al, bl);
      B0l[kt][d] = al; B1l[kt][d] = bl;
    }
  }

  floatx16 g2a, g2b;
#pragma unroll
  for (int i = 0; i < 16; i++) { g2a[i] = 0.f; g2b[i] = 0.f; }

  const float4* bp = (const float4*)bfc0;  // 512 B, L1-resident

#pragma unroll
  for (int Mt = 0; Mt < 4; Mt++) {
    half8 Ah[3], Al[3];
#pragma unroll
    for (int kt = 0; kt < 3; kt++) {
      Ah[kt] = *(const half8*)&s_wf[((Mt * 3 + kt) * 2 + 0) * 512 + lane * 8];
      Al[kt] = *(const half8*)&s_wf[((Mt * 3 + kt) * 2 + 1) * 512 + lane * 8];
    }
    // bias init per D-reg r=8u+s: logical unit = 32*Mt + 16*u + 8*h8 + s
    const float4 bb0 = bp[Mt * 8 + 2 * h8];
    const float4 bb1 = bp[Mt * 8 + 2 * h8 + 1];
    const float4 bb2 = bp[Mt * 8 + 4 + 2 * h8];
    const float4 bb3 = bp[Mt * 8 + 4 + 2 * h8 + 1];
    floatx16 acc0 = { bb0.x, bb0.y, bb0.z, bb0.w, bb1.x, bb1.y, bb1.z, bb1.w,
                      bb2.x, bb2.y, bb2.z, bb2.w, bb3.x, bb3.y, bb3.z, bb3.w };
    floatx16 acc1 = acc0;

#pragma unroll
    for (int kt = 0; kt < 3; kt++) {
      const half8 b0h = mk8(B0h[kt][0], B0h[kt][1], B0h[kt][2], B0h[kt][3]);
      const half8 b0l = mk8(B0l[kt][0], B0l[kt][1], B0l[kt][2], B0l[kt][3]);
      const half8 b1h = mk8(B1h[kt][0], B1h[kt][1], B1h[kt][2], B1h[kt][3]);
      const half8 b1l = mk8(B1l[kt][0], B1l[kt][1], B1l[kt][2], B1l[kt][3]);
      acc0 = __builtin_amdgcn_mfma_f32_32x32x16_f16(Ah[kt], b0h, acc0, 0, 0, 0);
      acc0 = __builtin_amdgcn_mfma_f32_32x32x16_f16(Al[kt], b0h, acc0, 0, 0, 0);
      acc0 = __builtin_amdgcn_mfma_f32_32x32x16_f16(Ah[kt], b0l, acc0, 0, 0, 0);
      acc1 = __builtin_amdgcn_mfma_f32_32x32x16_f16(Ah[kt], b1h, acc1, 0, 0, 0);
      acc1 = __builtin_amdgcn_mfma_f32_32x32x16_f16(Al[kt], b1h, acc1, 0, 0, 0);
      acc1 = __builtin_amdgcn_mfma_f32_32x32x16_f16(Ah[kt], b1l, acc1, 0, 0, 0);
    }

    // ---- H-transform + GEMM2: acc reg 8u+s holds the logical unit for
    // B2 k-slot s (thanks to the W0 permutation) -> no shuffles, no selects.
#pragma unroll
    for (int u = 0; u < 2; u++) {
      const int kt2 = 2 * Mt + u;
      const half8 W1h = *(const half8*)&s_wf[12288 + (kt2 * 2 + 0) * 512 + lane * 8];
      const half8 W1l = *(const half8*)&s_wf[12288 + (kt2 * 2 + 1) * 512 + lane * 8];
#pragma unroll
      for (int nt = 0; nt < 2; nt++) {
        float hv[8];
#pragma unroll
        for (int s = 0; s < 8; s++) {
          const float v = nt ? acc1[8 * u + s] : acc0[8 * u + s];
          hv[s] = fmaxf(v, 0.f);
        }
        uint32_t pkh[4], pkl[4];
#pragma unroll
        for (int d = 0; d < 4; d++) {
          const float a = hv[2 * d], bq = hv[2 * d + 1];
          const _Float16 ah = (_Float16)a, bh = (_Float16)bq;
          const _Float16 al = (_Float16)(a - (float)ah), bl = (_Float16)(bq - (float)bh);
          pkh[d] = pk2(ah, bh);
          pkl[d] = pk2(al, bl);
        }
        const half8 Bh2 = mk8(pkh[0], pkh[1], pkh[2], pkh[3]);
        const half8 Bl2 = mk8(pkl[0], pkl[1], pkl[2], pkl[3]);
        if (nt == 0) {
          g2a = __builtin_amdgcn_mfma_f32_32x32x16_f16(W1h, Bh2, g2a, 0, 0, 0);
          g2a = __builtin_amdgcn_mfma_f32_32x32x16_f16(W1l, Bh2, g2a, 0, 0, 0);
          g2a = __builtin_amdgcn_mfma_f32_32x32x16_f16(W1h, Bl2, g2a, 0, 0, 0);
        } else {
          g2b = __builtin_amdgcn_mfma_f32_32x32x16_f16(W1h, Bh2, g2b, 0, 0, 0);
          g2b = __builtin_amdgcn_mfma_f32_32x32x16_f16(W1l, Bh2, g2b, 0, 0, 0);
          g2b = __builtin_amdgcn_mfma_f32_32x32x16_f16(W1h, Bl2, g2b, 0, 0, 0);
        }
      }
    }
  }

  // ---- epilogue: h8=0 regs = ch 3..7; h8=1 regs = ch 8..15. No shuffles.
#pragma unroll
  for (int nt = 0; nt < 2; nt++) {
    float dxv[8];
#pragma unroll
    for (int i = 0; i < 8; i++) dxv[i] = nt ? g2b[i] : g2a[i];
    const uint32_t p = wbase + (uint32_t)(nt * 32) + (uint32_t)ln31;
    uint32_t t0, t1;
    threefry2x32(key0, key1, 0u, p, t0, t1);
    const uint32_t bits = t0 ^ t1;
    const float uu = __uint_as_float((bits >> 9) | 0x3f800000u) - 1.0f;
    const float M = (uu <= 0.5f) ? 1.f : 0.f;
    const float4* sp = (const float4*)(in + (size_t)p * 16);
    const float4 sA = sp[2 * h8];
    const float4 sB = sp[2 * h8 + 1];
    float4 oA, oB;
    oA.x = h8 ? fmaf(M, dxv[0], sA.x) : sA.x;                  // ch8  | ch0
    oA.y = h8 ? fmaf(M, dxv[1], sA.y) : sA.y;                  // ch9  | ch1
    oA.z = h8 ? fmaf(M, dxv[2], sA.z) : sA.z;                  // ch10 | ch2
    oA.w = fmaf(M, h8 ? dxv[3] : dxv[0], sA.w);                // ch11 | ch3
    oB.x = fmaf(M, h8 ? dxv[4] : dxv[1], sB.x);                // ch12 | ch4
    oB.y = fmaf(M, h8 ? dxv[5] : dxv[2], sB.y);                // ch13 | ch5
    oB.z = fmaf(M, h8 ? dxv[6] : dxv[3], sB.z);                // ch14 | ch6
    oB.w = fmaf(M, h8 ? dxv[7] : dxv[4], sB.w);                // ch15 | ch7
    float4* dp = (float4*)(out + (size_t)p * 16);
    dp[2 * h8] = oA;
    dp[2 * h8 + 1] = oB;
  }
}

// ---------------- NHWC state -> (out slice, x_final NCHW) ----------------
__global__ __launch_bounds__(256) void k_nhwc_to_out(const float* __restrict__ st,
                                                     float* __restrict__ outp) {
  const int p = blockIdx.x * 256 + threadIdx.x;
  const int b = p >> 16;
  const int hw = p & 65535;
  const float4* src = (const float4*)(st + (size_t)p * 16);
  float v[16];
#pragma unroll
  for (int q = 0; q < 4; q++) {
    float4 t = src[q];
    v[4 * q] = t.x; v[4 * q + 1] = t.y; v[4 * q + 2] = t.z; v[4 * q + 3] = t.w;
  }
  float* xf = outp + NPIX;  // x_final region of d_out
#pragma unroll
  for (int c = 0; c < 16; c++) xf[(size_t)(b * 16 + c) * HW + hw] = v[c];
  outp[(size_t)b * HW + hw] = v[3];  // out = x_final[:, 3:4]
}

extern "C" void kernel_launch(void* const* d_in, const int* in_sizes, int n_in,
                              void* d_out, int out_size, void* d_ws, size_t ws_size,
                              hipStream_t stream) {
  const float* x    = (const float*)d_in[0];
  const float* wp0  = (const float*)d_in[1];
  const float* wp1  = (const float*)d_in[2];
  const float* wfc0 = (const float*)d_in[3];
  const float* bfc0 = (const float*)d_in[4];
  const float* wfc1 = (const float*)d_in[5];
  float* out = (float*)d_out;

  unsigned short* wf = (unsigned short*)d_ws;          // 20480 f16 (40960 B)
  float* S0 = (float*)((char*)d_ws + 65536);           // 33.5 MB scratch state
  float* S1 = out + NPIX;                              // x_final region as scratch

  // Step keys: foldlike split of key(42): keys[s] = threefry((0,42),(0,s))
  uint32_t k0[NSTEPS], k1[NSTEPS];
  for (int s = 0; s < NSTEPS; s++)
    threefry2x32(0u, 42u, 0u, (uint32_t)s, k0[s], k1[s]);

  dim3 block(256);
  hipLaunchKernelGGL(k_prep, dim3(80), block, 0, stream, wfc0, wfc1, wf);
  hipLaunchKernelGGL(k_nchw_to_nhwc, dim3(NPIX / 256), block, 0, stream, x, S0);
  float* cur = S0;
  float* nxt = S1;
  for (int s = 0; s < NSTEPS; s++) {
    hipLaunchKernelGGL(k_step, dim3(Bn * Hh), block, 0, stream,
                       cur, nxt, wp0, wp1, wf, bfc0, k0[s], k1[s]);
    float* t = cur; cur = nxt; nxt = t;
  }
  // 32 steps (even) -> final state back in S0
  hipLaunchKernelGGL(k_nhwc_to_out, dim3(NPIX / 256), block, 0, stream, cur, out);
}